// Round 1
// baseline (780.570 us; speedup 1.0000x reference)
//
#include <hip/hip_runtime.h>

#define BB 8
#define CC 1024
#define FF 256
#define NHH 8
#define OFF 128
#define NHOF 1024
#define KSCALE 0.9617966939259756f  // log2(e)/1.5
#define NEG -1.0e9f

// ---------------- Kernel 1: dual GEMM  Wh = H@W ; res = H@res_W + b ----------------
// M=8192, K=256, N=1024 each. Tile 128x128, microtile 8x8, K-step 16.
__global__ __launch_bounds__(256) void k_gemm(const float* __restrict__ H,
    const float* __restrict__ W, const float* __restrict__ RW,
    const float* __restrict__ rb, float* __restrict__ Wh, float* __restrict__ Rs)
{
  __shared__ float As[16 * 128];  // transposed [k][m]
  __shared__ float Bs[16 * 128];  // [k][n]
  const int t = threadIdx.x;
  const int ty = t >> 4, tx = t & 15;
  const int m0 = blockIdx.y * 128;
  const int nb = blockIdx.x;            // 0..7 -> W, 8..15 -> res_W
  const float* Bsrc = (nb < 8) ? W : RW;
  const int n0 = (nb & 7) * 128;

  float acc[8][8];
#pragma unroll
  for (int r = 0; r < 8; ++r)
#pragma unroll
    for (int c = 0; c < 8; ++c) acc[r][c] = 0.f;

  for (int k0 = 0; k0 < FF; k0 += 16) {
#pragma unroll
    for (int ch = 0; ch < 2; ++ch) {   // A tile 128 rows x 16 k, store transposed
      int c = t + ch * 256;
      int row = c >> 2, kq = (c & 3) << 2;
      float4 v = *reinterpret_cast<const float4*>(H + (size_t)(m0 + row) * FF + k0 + kq);
      As[(kq + 0) * 128 + row] = v.x;
      As[(kq + 1) * 128 + row] = v.y;
      As[(kq + 2) * 128 + row] = v.z;
      As[(kq + 3) * 128 + row] = v.w;
    }
#pragma unroll
    for (int ch = 0; ch < 2; ++ch) {   // B tile 16 k x 128 n
      int c = t + ch * 256;
      int kr = c >> 5, nq = (c & 31) << 2;
      *reinterpret_cast<float4*>(Bs + kr * 128 + nq) =
          *reinterpret_cast<const float4*>(Bsrc + (size_t)(k0 + kr) * NHOF + n0 + nq);
    }
    __syncthreads();
#pragma unroll
    for (int kk = 0; kk < 16; ++kk) {
      float aF[8], bF[8];
      *reinterpret_cast<float4*>(&aF[0]) = *reinterpret_cast<float4*>(As + kk * 128 + ty * 8);
      *reinterpret_cast<float4*>(&aF[4]) = *reinterpret_cast<float4*>(As + kk * 128 + ty * 8 + 4);
      *reinterpret_cast<float4*>(&bF[0]) = *reinterpret_cast<float4*>(Bs + kk * 128 + tx * 8);
      *reinterpret_cast<float4*>(&bF[4]) = *reinterpret_cast<float4*>(Bs + kk * 128 + tx * 8 + 4);
#pragma unroll
      for (int r = 0; r < 8; ++r)
#pragma unroll
        for (int c = 0; c < 8; ++c) acc[r][c] = fmaf(aF[r], bF[c], acc[r][c]);
    }
    __syncthreads();
  }

  if (nb < 8) {
#pragma unroll
    for (int r = 0; r < 8; ++r) {
      size_t g = (size_t)(m0 + ty * 8 + r) * NHOF + n0 + tx * 8;
      *reinterpret_cast<float4*>(Wh + g)     = make_float4(acc[r][0], acc[r][1], acc[r][2], acc[r][3]);
      *reinterpret_cast<float4*>(Wh + g + 4) = make_float4(acc[r][4], acc[r][5], acc[r][6], acc[r][7]);
    }
  } else {
    float b0[8];
#pragma unroll
    for (int c = 0; c < 8; ++c) b0[c] = rb[n0 + tx * 8 + c];
#pragma unroll
    for (int r = 0; r < 8; ++r) {
      size_t g = (size_t)(m0 + ty * 8 + r) * NHOF + n0 + tx * 8;
      *reinterpret_cast<float4*>(Rs + g)     = make_float4(acc[r][0] + b0[0], acc[r][1] + b0[1], acc[r][2] + b0[2], acc[r][3] + b0[3]);
      *reinterpret_cast<float4*>(Rs + g + 4) = make_float4(acc[r][4] + b0[4], acc[r][5] + b0[5], acc[r][6] + b0[6], acc[r][7] + b0[7]);
    }
  }
}

// ---------------- Kernel 2: e_src / e_dst ----------------
__global__ __launch_bounds__(256) void k_srcdst(const float* __restrict__ Wh,
    const float* __restrict__ a, float* __restrict__ es, float* __restrict__ ed)
{
  const int row = blockIdx.x;           // b*C + c
  const int t = threadIdx.x;
  const int h = t >> 5, l = t & 31;
  const float* wr = Wh + (size_t)row * NHOF + h * OFF + l * 4;
  const float* ah = a + h * 2 * OFF + l * 4;
  float4 w  = *reinterpret_cast<const float4*>(wr);
  float4 as = *reinterpret_cast<const float4*>(ah);
  float4 ad = *reinterpret_cast<const float4*>(ah + OFF);
  float ps = w.x * as.x + w.y * as.y + w.z * as.z + w.w * as.w;
  float pd = w.x * ad.x + w.y * ad.y + w.z * ad.z + w.w * ad.w;
#pragma unroll
  for (int m = 16; m; m >>= 1) { ps += __shfl_xor(ps, m); pd += __shfl_xor(pd, m); }
  if (l == 0) { es[row * 8 + h] = ps; ed[row * 8 + h] = pd; }
}

// ---------------- Kernel 3: A row-sum reciprocals ----------------
__global__ __launch_bounds__(256) void k_rowsum(const float* __restrict__ A, float* __restrict__ rsi)
{
  __shared__ float sm[4];
  const int row = blockIdx.x;
  const int t = threadIdx.x;
  float4 v = *reinterpret_cast<const float4*>(A + (size_t)row * CC + t * 4);
  float s = v.x + v.y + v.z + v.w;
#pragma unroll
  for (int m = 32; m; m >>= 1) s += __shfl_xor(s, m);
  if ((t & 63) == 0) sm[t >> 6] = s;
  __syncthreads();
  if (t == 0) rsi[row] = 1.f / (sm[0] + sm[1] + sm[2] + sm[3] + 1e-8f);
}

// ---------------- Kernel 4: fused scores + softmax + alpha-out + PV ----------------
// One block per (b, 32-row i-tile). 1024 threads, 43KB LDS.
__global__ __launch_bounds__(1024) void k_attn(const float* __restrict__ A,
    const float* __restrict__ Wh, const float* __restrict__ es,
    const float* __restrict__ ed, const float* __restrict__ rsi,
    float* __restrict__ alp, float* __restrict__ ho)
{
  __shared__ float smU[8192];        // pass1: e_dst^T [h][j] ; pass2: Wh tile [8][1024]
  __shared__ float smAl[32 * 66];    // alpha tile [i][jl*8+h], row stride 66 (bank-spread)
  __shared__ float smEs[256];        // e_src [i][h]
  __shared__ float smLi[256];        // 1/l [i][h]
  __shared__ float smRs[32];         // 1/(rowsum+eps)

  const int t = threadIdx.x;
  const int b = blockIdx.x >> 5;
  const int i0 = (blockIdx.x & 31) << 5;

  {  // stage e_dst transposed
    const float* edb = ed + (size_t)b * CC * 8 + (size_t)t * 8;
    float4 v0 = *reinterpret_cast<const float4*>(edb);
    float4 v1 = *reinterpret_cast<const float4*>(edb + 4);
    smU[0 * 1024 + t] = v0.x; smU[1 * 1024 + t] = v0.y;
    smU[2 * 1024 + t] = v0.z; smU[3 * 1024 + t] = v0.w;
    smU[4 * 1024 + t] = v1.x; smU[5 * 1024 + t] = v1.y;
    smU[6 * 1024 + t] = v1.z; smU[7 * 1024 + t] = v1.w;
  }
  if (t < 256) smEs[t] = es[(size_t)b * CC * 8 + i0 * 8 + t];
  if (t < 32)  smRs[t] = rsi[b * CC + i0 + t];
  __syncthreads();

  // ---- pass 1: softmax denominators (no max shift needed: e bounded ~[-5,5]) ----
  {
    const int i = t >> 5, js = t & 31;
    const float* Ar = A + ((size_t)b * CC + i0 + i) * CC;
    const float rs = smRs[i];
    float esr[8];
#pragma unroll
    for (int h = 0; h < 8; ++h) esr[h] = smEs[i * 8 + h];
    float ls[8] = {0, 0, 0, 0, 0, 0, 0, 0};
    for (int jj = 0; jj < 32; ++jj) {
      int j = js + (jj << 5);
      float aij = Ar[j];
      float an = aij * rs;
      bool mk = (aij > 0.f) | (j == i0 + i);
#pragma unroll
      for (int h = 0; h < 8; ++h) {
        float ee = esr[h] + smU[h * 1024 + j];
        ee = ee > 0.f ? ee : 0.2f * ee;
        float val = (mk ? ee : NEG) + an;
        ls[h] += exp2f(val * KSCALE);
      }
    }
#pragma unroll
    for (int h = 0; h < 8; ++h) {
      float v = ls[h];
#pragma unroll
      for (int m = 16; m; m >>= 1) v += __shfl_xor(v, m);
      if (js == 0) smLi[i * 8 + h] = 1.f / v;
    }
  }
  __syncthreads();

  // ---- pass 2: alpha + PV over j-tiles of 8 ----
  const int h = t >> 7, r = t & 127;
  const int ig = r >> 4, fg = r & 15, f0 = fg << 3;
  float acc[4][8];
#pragma unroll
  for (int ii = 0; ii < 4; ++ii)
#pragma unroll
    for (int c = 0; c < 8; ++c) acc[ii][c] = 0.f;

  const float* Whb = Wh + (size_t)b * CC * NHOF;
  const float* edb = ed + (size_t)b * CC * 8;

  for (int j0 = 0; j0 < CC; j0 += 8) {
    {  // stage Wh tile [8][1024] into smU
      int jl = t >> 7, off = (t & 127) << 3;
      const float* src = Whb + (size_t)(j0 + jl) * NHOF + off;
      float4 v0 = *reinterpret_cast<const float4*>(src);
      float4 v1 = *reinterpret_cast<const float4*>(src + 4);
      *reinterpret_cast<float4*>(smU + jl * 1024 + off)     = v0;
      *reinterpret_cast<float4*>(smU + jl * 1024 + off + 4) = v1;
    }
    if (t < 256) {  // compute alpha tile, write to d_out + LDS
      int i2 = t >> 3, jl = t & 7, j = j0 + jl;
      float aij = A[((size_t)b * CC + i0 + i2) * CC + j];
      float an = aij * smRs[i2];
      bool mk = (aij > 0.f) | (j == i0 + i2);
      float av[8];
#pragma unroll
      for (int hh = 0; hh < 8; ++hh) {
        float ee = smEs[i2 * 8 + hh] + edb[(size_t)j * 8 + hh];
        ee = ee > 0.f ? ee : 0.2f * ee;
        float val = (mk ? ee : NEG) + an;
        av[hh] = exp2f(val * KSCALE) * smLi[i2 * 8 + hh];
        smAl[i2 * 66 + jl * 8 + hh] = av[hh];
      }
      size_t g = (((size_t)b * CC + i0 + i2) * CC + j) * 8;
      *reinterpret_cast<float4*>(alp + g)     = make_float4(av[0], av[1], av[2], av[3]);
      *reinterpret_cast<float4*>(alp + g + 4) = make_float4(av[4], av[5], av[6], av[7]);
    }
    __syncthreads();
#pragma unroll
    for (int jl = 0; jl < 8; ++jl) {  // PV accumulate
      float w[8];
      *reinterpret_cast<float4*>(&w[0]) = *reinterpret_cast<float4*>(smU + jl * 1024 + h * OFF + f0);
      *reinterpret_cast<float4*>(&w[4]) = *reinterpret_cast<float4*>(smU + jl * 1024 + h * OFF + f0 + 4);
#pragma unroll
      for (int ii = 0; ii < 4; ++ii) {
        float al = smAl[(ig * 4 + ii) * 66 + jl * 8 + h];
#pragma unroll
        for (int c = 0; c < 8; ++c) acc[ii][c] = fmaf(al, w[c], acc[ii][c]);
      }
    }
    __syncthreads();
  }
#pragma unroll
  for (int ii = 0; ii < 4; ++ii) {
    size_t g = ((size_t)b * CC + i0 + ig * 4 + ii) * NHOF + h * OFF + f0;
    *reinterpret_cast<float4*>(ho + g)     = make_float4(acc[ii][0], acc[ii][1], acc[ii][2], acc[ii][3]);
    *reinterpret_cast<float4*>(ho + g + 4) = make_float4(acc[ii][4], acc[ii][5], acc[ii][6], acc[ii][7]);
  }
}

// ---------------- Kernel 5: x = H_out + res ; LayerNorm ; ReLU (in-place on out0) ----------------
__global__ __launch_bounds__(256) void k_ln(const float* __restrict__ Rs,
    const float* __restrict__ g, const float* __restrict__ bt, float* __restrict__ out)
{
  __shared__ float sm[8];
  const int row = blockIdx.x;
  const int t = threadIdx.x;
  size_t base = (size_t)row * NHOF + t * 4;
  float4 hv = *reinterpret_cast<const float4*>(out + base);
  float4 rv = *reinterpret_cast<const float4*>(Rs + base);
  float x0 = hv.x + rv.x, x1 = hv.y + rv.y, x2 = hv.z + rv.z, x3 = hv.w + rv.w;
  float s  = x0 + x1 + x2 + x3;
  float ss = x0 * x0 + x1 * x1 + x2 * x2 + x3 * x3;
#pragma unroll
  for (int m = 32; m; m >>= 1) { s += __shfl_xor(s, m); ss += __shfl_xor(ss, m); }
  if ((t & 63) == 0) { sm[t >> 6] = s; sm[4 + (t >> 6)] = ss; }
  __syncthreads();
  s  = sm[0] + sm[1] + sm[2] + sm[3];
  ss = sm[4] + sm[5] + sm[6] + sm[7];
  float mu = s * (1.f / 1024.f);
  float var = ss * (1.f / 1024.f) - mu * mu;
  float rstd = rsqrtf(var + 1e-5f);
  float4 gv = *reinterpret_cast<const float4*>(g + t * 4);
  float4 bv = *reinterpret_cast<const float4*>(bt + t * 4);
  float y0 = fmaxf((x0 - mu) * rstd * gv.x + bv.x, 0.f);
  float y1 = fmaxf((x1 - mu) * rstd * gv.y + bv.y, 0.f);
  float y2 = fmaxf((x2 - mu) * rstd * gv.z + bv.z, 0.f);
  float y3 = fmaxf((x3 - mu) * rstd * gv.w + bv.w, 0.f);
  *reinterpret_cast<float4*>(out + base) = make_float4(y0, y1, y2, y3);
}

extern "C" void kernel_launch(void* const* d_in, const int* in_sizes, int n_in,
                              void* d_out, int out_size, void* d_ws, size_t ws_size,
                              hipStream_t stream) {
  const float* H    = (const float*)d_in[0];
  const float* A    = (const float*)d_in[1];
  const float* W    = (const float*)d_in[2];
  const float* a    = (const float*)d_in[3];
  const float* resW = (const float*)d_in[4];
  const float* resb = (const float*)d_in[5];
  const float* gam  = (const float*)d_in[6];
  const float* bet  = (const float*)d_in[7];

  float* out0  = (float*)d_out;                       // relu(x): 8*1024*1024
  float* alpha = out0 + (size_t)BB * CC * NHOF;       // alpha:   8*1024*1024*8

  float* Wh   = (float*)d_ws;                         // 8,388,608 f
  float* res  = Wh + (size_t)BB * CC * NHOF;          // 8,388,608 f
  float* esrc = res + (size_t)BB * CC * NHOF;         // 65,536 f
  float* edst = esrc + (size_t)BB * CC * NHH;         // 65,536 f
  float* rsin = edst + (size_t)BB * CC * NHH;         // 8,192 f

  k_gemm  <<<dim3(16, 64), 256, 0, stream>>>(H, W, resW, resb, Wh, res);
  k_srcdst<<<BB * CC, 256, 0, stream>>>(Wh, a, esrc, edst);
  k_rowsum<<<BB * CC, 256, 0, stream>>>(A, rsin);
  k_attn  <<<BB * 32, 1024, 0, stream>>>(A, Wh, esrc, edst, rsin, alpha, out0);
  k_ln    <<<BB * CC, 256, 0, stream>>>(res, gam, bet, out0);
}

// Round 3
// 527.235 us; speedup vs baseline: 1.4805x; 1.4805x over previous
//
#include <hip/hip_runtime.h>

#define BB 8
#define CC 1024
#define FF 256
#define NHH 8
#define OFF 128
#define NHOF 1024
#define KSCALE 0.9617966939259756f  // log2(e)/1.5

typedef __attribute__((ext_vector_type(8))) short s8v;
typedef __attribute__((ext_vector_type(4))) short s4v;
typedef __attribute__((ext_vector_type(2))) short s2v;
typedef __attribute__((ext_vector_type(4))) float f32x4;
typedef __attribute__((ext_vector_type(16))) float f32x16;

__device__ __forceinline__ ushort f2b(float f) {
  union { float f; uint u; } v; v.f = f;
  uint r = v.u + 0x7FFFu + ((v.u >> 16) & 1u);
  return (ushort)(r >> 16);
}

// ---------------- Kernel 0: transpose+cast W,res_W -> Wt,RWt bf16 [n][k] ----------------
__global__ __launch_bounds__(256) void k_prep(const float* __restrict__ W,
    const float* __restrict__ RW, short* __restrict__ Wt, short* __restrict__ RWt)
{
  __shared__ float st[32][33];
  const float* src = blockIdx.z ? RW : W;
  short* dst = blockIdx.z ? RWt : Wt;
  const int n0 = blockIdx.x * 32, k0 = blockIdx.y * 32;
  const int t = threadIdx.x;
  {
    int kr = t >> 3, nq = (t & 7) * 4;
    float4 v = *reinterpret_cast<const float4*>(src + (size_t)(k0 + kr) * NHOF + n0 + nq);
    st[kr][nq] = v.x; st[kr][nq + 1] = v.y; st[kr][nq + 2] = v.z; st[kr][nq + 3] = v.w;
  }
  __syncthreads();
  {
    int nr = t >> 3, kq = (t & 7) * 4;
    s4v pk;
    pk[0] = (short)f2b(st[kq + 0][nr]); pk[1] = (short)f2b(st[kq + 1][nr]);
    pk[2] = (short)f2b(st[kq + 2][nr]); pk[3] = (short)f2b(st[kq + 3][nr]);
    *reinterpret_cast<s4v*>(dst + (size_t)(n0 + nr) * FF + k0 + kq) = pk;
  }
}

// ---------------- Kernel 1: MFMA dual GEMM + e_src/e_dst epilogue ----------------
// nb 0..7: Wh = H@W -> Wh_t bf16 [b][h][f][j], + e_src/e_dst from f32 acc
// nb 8..15: res = H@res_W + b (f32)
__global__ __launch_bounds__(256) void k_gemm(const float* __restrict__ H,
    const short* __restrict__ Wt, const short* __restrict__ RWt,
    const float* __restrict__ rb, const float* __restrict__ att,
    short* __restrict__ WhT, float* __restrict__ Rs,
    float* __restrict__ esg, float* __restrict__ edg)
{
  __shared__ short As[128 * 32];
  __shared__ short Bs[128 * 32];
  __shared__ float ep[2][128][2];
  const int t = threadIdx.x, l = t & 63, w = t >> 6;
  const int wr = w >> 1, wc = w & 1;
  const int nb = blockIdx.x, m0 = blockIdx.y * 128;
  const bool isW = nb < 8;
  const int n0 = (nb & 7) * 128;
  const short* Bg = isW ? Wt : RWt;

  f32x4 acc[4][4];
#pragma unroll
  for (int mi = 0; mi < 4; ++mi)
#pragma unroll
    for (int ni = 0; ni < 4; ++ni)
#pragma unroll
      for (int r = 0; r < 4; ++r) acc[mi][ni][r] = 0.f;

  const int srow = t >> 1, skh = (t & 1) * 16;
  const float* hsrc = H + (size_t)(m0 + srow) * FF + skh;
  const short* bsrc = Bg + (size_t)(n0 + srow) * FF + skh;
  const int fr = l & 15, kg = (l >> 4) * 8;

  for (int k0 = 0; k0 < FF; k0 += 32) {
    float4 h0 = *reinterpret_cast<const float4*>(hsrc + k0);
    float4 h1 = *reinterpret_cast<const float4*>(hsrc + k0 + 4);
    float4 h2 = *reinterpret_cast<const float4*>(hsrc + k0 + 8);
    float4 h3 = *reinterpret_cast<const float4*>(hsrc + k0 + 12);
    s8v b0 = *reinterpret_cast<const s8v*>(bsrc + k0);
    s8v b1 = *reinterpret_cast<const s8v*>(bsrc + k0 + 8);
    s8v p0, p1;
    p0[0] = (short)f2b(h0.x); p0[1] = (short)f2b(h0.y); p0[2] = (short)f2b(h0.z); p0[3] = (short)f2b(h0.w);
    p0[4] = (short)f2b(h1.x); p0[5] = (short)f2b(h1.y); p0[6] = (short)f2b(h1.z); p0[7] = (short)f2b(h1.w);
    p1[0] = (short)f2b(h2.x); p1[1] = (short)f2b(h2.y); p1[2] = (short)f2b(h2.z); p1[3] = (short)f2b(h2.w);
    p1[4] = (short)f2b(h3.x); p1[5] = (short)f2b(h3.y); p1[6] = (short)f2b(h3.z); p1[7] = (short)f2b(h3.w);
    *reinterpret_cast<s8v*>(As + srow * 32 + skh) = p0;
    *reinterpret_cast<s8v*>(As + srow * 32 + skh + 8) = p1;
    *reinterpret_cast<s8v*>(Bs + srow * 32 + skh) = b0;
    *reinterpret_cast<s8v*>(Bs + srow * 32 + skh + 8) = b1;
    __syncthreads();
    s8v aF[4], bF[4];
#pragma unroll
    for (int mi = 0; mi < 4; ++mi)
      aF[mi] = *reinterpret_cast<const s8v*>(As + (wr * 64 + mi * 16 + fr) * 32 + kg);
#pragma unroll
    for (int ni = 0; ni < 4; ++ni)
      bF[ni] = *reinterpret_cast<const s8v*>(Bs + (wc * 64 + ni * 16 + fr) * 32 + kg);
#pragma unroll
    for (int mi = 0; mi < 4; ++mi)
#pragma unroll
      for (int ni = 0; ni < 4; ++ni)
        acc[mi][ni] = __builtin_amdgcn_mfma_f32_16x16x32_bf16(aF[mi], bF[ni], acc[mi][ni], 0, 0, 0);
    __syncthreads();
  }

  const int bb = m0 >> 10, jl0 = m0 & 1023;
  if (isW) {
    const int h = nb;
    // Wh_t bf16 write: lane holds 4 consecutive j (rows) at fixed f (col)
#pragma unroll
    for (int mi = 0; mi < 4; ++mi)
#pragma unroll
      for (int ni = 0; ni < 4; ++ni) {
        int f = wc * 64 + ni * 16 + (l & 15);
        int j = jl0 + wr * 64 + mi * 16 + (l >> 4) * 4;
        s4v pk;
        pk[0] = (short)f2b(acc[mi][ni][0]); pk[1] = (short)f2b(acc[mi][ni][1]);
        pk[2] = (short)f2b(acc[mi][ni][2]); pk[3] = (short)f2b(acc[mi][ni][3]);
        *reinterpret_cast<s4v*>(WhT + (size_t)((bb * 8 + h) * 128 + f) * 1024 + j) = pk;
      }
    // e_src/e_dst partials from f32 acc
    float aS[4], aD[4];
#pragma unroll
    for (int ni = 0; ni < 4; ++ni) {
      int f = wc * 64 + ni * 16 + (l & 15);
      aS[ni] = att[h * 256 + f];
      aD[ni] = att[h * 256 + 128 + f];
    }
#pragma unroll
    for (int mi = 0; mi < 4; ++mi)
#pragma unroll
      for (int r = 0; r < 4; ++r) {
        float ps = acc[mi][0][r] * aS[0] + acc[mi][1][r] * aS[1] + acc[mi][2][r] * aS[2] + acc[mi][3][r] * aS[3];
        float pd = acc[mi][0][r] * aD[0] + acc[mi][1][r] * aD[1] + acc[mi][2][r] * aD[2] + acc[mi][3][r] * aD[3];
#pragma unroll
        for (int m = 1; m <= 8; m <<= 1) { ps += __shfl_xor(ps, m); pd += __shfl_xor(pd, m); }
        if ((l & 15) == 0) {
          int row = wr * 64 + mi * 16 + (l >> 4) * 4 + r;
          ep[wc][row][0] = ps; ep[wc][row][1] = pd;
        }
      }
    __syncthreads();
    {
      int row = t >> 1, sel = t & 1;
      float v = ep[0][row][sel] + ep[1][row][sel];
      float* dst = sel ? edg : esg;
      dst[(size_t)((bb << 10) + jl0 + row) * 8 + h] = v;
    }
  } else {
#pragma unroll
    for (int mi = 0; mi < 4; ++mi)
#pragma unroll
      for (int ni = 0; ni < 4; ++ni) {
        int n = n0 + wc * 64 + ni * 16 + (l & 15);
        float bias = rb[n];
        int m = m0 + wr * 64 + mi * 16 + (l >> 4) * 4;
#pragma unroll
        for (int r = 0; r < 4; ++r)
          Rs[(size_t)(m + r) * NHOF + n] = acc[mi][ni][r] + bias;
      }
  }
}

// ---------------- Kernel 2: fused rowsum + softmax + alpha-out + MFMA PV ----------------
// grid 256 = (b, 32-row i-tile); 256 threads (4 waves); 74.3KB LDS -> 2 blocks/CU
__global__ __launch_bounds__(256, 2) void k_attn(const float* __restrict__ A,
    const short* __restrict__ WhT, const float* __restrict__ esg,
    const float* __restrict__ edg, float* __restrict__ alp, float* __restrict__ ho)
{
  __shared__ short WhS[1024 * 16];   // [h*128+f][16 j] bf16, 32KB
  __shared__ float edK[8 * 1028];    // e_dst*K [h][j], padded stride, 32.9KB
  __shared__ short alS[8 * 32 * 16]; // alpha bf16 [h][i][16 j], 8KB
  __shared__ float esK[32 * 8];
  __shared__ float liS[32 * 8];
  __shared__ float rsS[32];

  const int t = threadIdx.x, l = t & 63, w = t >> 6;
  const int b = blockIdx.x >> 5, i0 = (blockIdx.x & 31) << 5;

  // stage scaled e_dst^T and e_src
#pragma unroll
  for (int c = 0; c < 32; ++c) {
    int idx = t + c * 256;
    int j = idx >> 3, h = idx & 7;
    edK[h * 1028 + j] = edg[(size_t)b * 8192 + idx] * KSCALE;
  }
  {
    int i = t >> 3, h = t & 7;
    esK[t] = esg[(size_t)((b << 10) + i0 + i) * 8 + h] * KSCALE;
  }

  // pass 0: A row sums
  {
    int i = w * 8 + (l >> 3), jsub = l & 7;
    const float* Ar = A + (size_t)((b << 10) + i0 + i) * 1024;
    float s = 0.f;
#pragma unroll
    for (int c = 0; c < 32; ++c) {
      float4 v = *reinterpret_cast<const float4*>(Ar + jsub * 4 + c * 32);
      s += v.x + v.y + v.z + v.w;
    }
    s += __shfl_xor(s, 1); s += __shfl_xor(s, 2); s += __shfl_xor(s, 4);
    if (jsub == 0) rsS[i] = 1.f / (s + 1e-8f);
  }
  __syncthreads();

  // pass 1: softmax denominators (no max shift: e bounded ~[-5,5])
  {
    const int i = t >> 3, jsub = t & 7, ig = i0 + i;
    const float* Ar = A + (size_t)((b << 10) + ig) * 1024;
    const float rs = rsS[i];
    float eK[8];
#pragma unroll
    for (int h = 0; h < 8; ++h) eK[h] = esK[i * 8 + h];
    float lac[8] = {0, 0, 0, 0, 0, 0, 0, 0};
    for (int jq = 0; jq < 32; ++jq) {
      int j = jq * 32 + jsub * 4;
      float4 av4 = *reinterpret_cast<const float4*>(Ar + j);
      float ea0 = (av4.x > 0.f || (j + 0) == ig) ? exp2f(av4.x * rs * KSCALE) : 0.f;
      float ea1 = (av4.y > 0.f || (j + 1) == ig) ? exp2f(av4.y * rs * KSCALE) : 0.f;
      float ea2 = (av4.z > 0.f || (j + 2) == ig) ? exp2f(av4.z * rs * KSCALE) : 0.f;
      float ea3 = (av4.w > 0.f || (j + 3) == ig) ? exp2f(av4.w * rs * KSCALE) : 0.f;
#pragma unroll
      for (int h = 0; h < 8; ++h) {
        const float* ed4 = edK + h * 1028 + j;
        float s0 = eK[h] + ed4[0]; s0 = fmaxf(s0, 0.2f * s0);
        float s1 = eK[h] + ed4[1]; s1 = fmaxf(s1, 0.2f * s1);
        float s2 = eK[h] + ed4[2]; s2 = fmaxf(s2, 0.2f * s2);
        float s3 = eK[h] + ed4[3]; s3 = fmaxf(s3, 0.2f * s3);
        lac[h] = fmaf(exp2f(s0), ea0, lac[h]);
        lac[h] = fmaf(exp2f(s1), ea1, lac[h]);
        lac[h] = fmaf(exp2f(s2), ea2, lac[h]);
        lac[h] = fmaf(exp2f(s3), ea3, lac[h]);
      }
    }
#pragma unroll
    for (int h = 0; h < 8; ++h) {
      float v = lac[h];
      v += __shfl_xor(v, 1); v += __shfl_xor(v, 2); v += __shfl_xor(v, 4);
      if (jsub == 0) liS[i * 8 + h] = 1.f / v;
    }
  }
  __syncthreads();

  // pass 2: per 16-j step: produce alpha (f32 out + bf16 LDS) then MFMA PV
  const int h0 = w * 2;
  f32x16 acc[2][4];
#pragma unroll
  for (int hh = 0; hh < 2; ++hh)
#pragma unroll
    for (int ff = 0; ff < 4; ++ff)
#pragma unroll
      for (int r = 0; r < 16; ++r) acc[hh][ff][r] = 0.f;

  const int i_p = t >> 3, jp = (t & 7) * 2, igP = i0 + i_p;
  const float rsP = rsS[i_p];
  float eKP[8], liP[8];
#pragma unroll
  for (int h = 0; h < 8; ++h) { eKP[h] = esK[i_p * 8 + h]; liP[h] = liS[i_p * 8 + h]; }
  const float* ArP = A + (size_t)((b << 10) + igP) * 1024;
  const short* Whb = WhT + (size_t)b * 1048576;

  for (int j0 = 0; j0 < 1024; j0 += 16) {
    // issue Wh_t global loads (consumed after producer compute: latency hidden)
    s8v sreg[8];
#pragma unroll
    for (int c = 0; c < 4; ++c) {
      const short* src = Whb + (size_t)(t + c * 256) * 1024 + j0;
      sreg[c * 2] = *reinterpret_cast<const s8v*>(src);
      sreg[c * 2 + 1] = *reinterpret_cast<const s8v*>(src + 8);
    }
    // producer: alpha for (i_p, j0+jp, j0+jp+1) x 8h
    float2 a2 = *reinterpret_cast<const float2*>(ArP + j0 + jp);
    float alo[2][8];
#pragma unroll
    for (int e = 0; e < 2; ++e) {
      float aij = e ? a2.y : a2.x;
      int j = j0 + jp + e;
      float ea = (aij > 0.f || j == igP) ? exp2f(aij * rsP * KSCALE) : 0.f;
#pragma unroll
      for (int h = 0; h < 8; ++h) {
        float s = eKP[h] + edK[h * 1028 + j];
        s = fmaxf(s, 0.2f * s);
        alo[e][h] = exp2f(s) * ea * liP[h];
      }
    }
    float* ap = alp + (size_t)((b << 10) + igP) * 8192 + (size_t)(j0 + jp) * 8;
    *reinterpret_cast<float4*>(ap)      = make_float4(alo[0][0], alo[0][1], alo[0][2], alo[0][3]);
    *reinterpret_cast<float4*>(ap + 4)  = make_float4(alo[0][4], alo[0][5], alo[0][6], alo[0][7]);
    *reinterpret_cast<float4*>(ap + 8)  = make_float4(alo[1][0], alo[1][1], alo[1][2], alo[1][3]);
    *reinterpret_cast<float4*>(ap + 12) = make_float4(alo[1][4], alo[1][5], alo[1][6], alo[1][7]);
#pragma unroll
    for (int h = 0; h < 8; ++h) {
      s2v pk; pk[0] = (short)f2b(alo[0][h]); pk[1] = (short)f2b(alo[1][h]);
      *reinterpret_cast<s2v*>(alS + h * 512 + i_p * 16 + jp) = pk;
    }
#pragma unroll
    for (int c = 0; c < 4; ++c) {
      *reinterpret_cast<s8v*>(WhS + (t + c * 256) * 16) = sreg[c * 2];
      *reinterpret_cast<s8v*>(WhS + (t + c * 256) * 16 + 8) = sreg[c * 2 + 1];
    }
    __syncthreads();
    // MFMA: 2 heads per wave, 32x32x16 bf16
#pragma unroll
    for (int hh = 0; hh < 2; ++hh) {
      int h = h0 + hh;
      s8v af = *reinterpret_cast<const s8v*>(alS + h * 512 + (l & 31) * 16 + (l >> 5) * 8);
#pragma unroll
      for (int ff = 0; ff < 4; ++ff) {
        s8v bf = *reinterpret_cast<const s8v*>(WhS + (h * 128 + ff * 32 + (l & 31)) * 16 + (l >> 5) * 8);
        acc[hh][ff] = __builtin_amdgcn_mfma_f32_32x32x16_bf16(af, bf, acc[hh][ff], 0, 0, 0);
      }
    }
    __syncthreads();
  }

  // epilogue: H_out
#pragma unroll
  for (int hh = 0; hh < 2; ++hh)
#pragma unroll
    for (int ff = 0; ff < 4; ++ff) {
      int f = ff * 32 + (l & 31);
      float* op = ho + (size_t)((b << 10) + i0) * 1024 + (h0 + hh) * 128 + f;
#pragma unroll
      for (int reg = 0; reg < 16; ++reg) {
        int irow = (reg & 3) + 8 * (reg >> 2) + 4 * (l >> 5);
        op[(size_t)irow * 1024] = acc[hh][ff][reg];
      }
    }
}

// ---------------- Kernel 3: x = H_out + res ; LayerNorm ; ReLU (in-place) ----------------
__global__ __launch_bounds__(256) void k_ln(const float* __restrict__ Rs,
    const float* __restrict__ g, const float* __restrict__ bt, float* __restrict__ out)
{
  __shared__ float sm[8];
  const int row = blockIdx.x;
  const int t = threadIdx.x;
  size_t base = (size_t)row * NHOF + t * 4;
  float4 hv = *reinterpret_cast<const float4*>(out + base);
  float4 rv = *reinterpret_cast<const float4*>(Rs + base);
  float x0 = hv.x + rv.x, x1 = hv.y + rv.y, x2 = hv.z + rv.z, x3 = hv.w + rv.w;
  float s  = x0 + x1 + x2 + x3;
  float ss = x0 * x0 + x1 * x1 + x2 * x2 + x3 * x3;
#pragma unroll
  for (int m = 32; m; m >>= 1) { s += __shfl_xor(s, m); ss += __shfl_xor(ss, m); }
  if ((t & 63) == 0) { sm[t >> 6] = s; sm[4 + (t >> 6)] = ss; }
  __syncthreads();
  s  = sm[0] + sm[1] + sm[2] + sm[3];
  ss = sm[4] + sm[5] + sm[6] + sm[7];
  float mu = s * (1.f / 1024.f);
  float var = ss * (1.f / 1024.f) - mu * mu;
  float rstd = rsqrtf(var + 1e-5f);
  float4 gv = *reinterpret_cast<const float4*>(g + t * 4);
  float4 bv = *reinterpret_cast<const float4*>(bt + t * 4);
  float y0 = fmaxf((x0 - mu) * rstd * gv.x + bv.x, 0.f);
  float y1 = fmaxf((x1 - mu) * rstd * gv.y + bv.y, 0.f);
  float y2 = fmaxf((x2 - mu) * rstd * gv.z + bv.z, 0.f);
  float y3 = fmaxf((x3 - mu) * rstd * gv.w + bv.w, 0.f);
  *reinterpret_cast<float4*>(out + base) = make_float4(y0, y1, y2, y3);
}

extern "C" void kernel_launch(void* const* d_in, const int* in_sizes, int n_in,
                              void* d_out, int out_size, void* d_ws, size_t ws_size,
                              hipStream_t stream) {
  const float* H    = (const float*)d_in[0];
  const float* A    = (const float*)d_in[1];
  const float* W    = (const float*)d_in[2];
  const float* av   = (const float*)d_in[3];
  const float* resW = (const float*)d_in[4];
  const float* resb = (const float*)d_in[5];
  const float* gam  = (const float*)d_in[6];
  const float* bet  = (const float*)d_in[7];

  float* out0  = (float*)d_out;                       // relu(x): 8*1024*1024 f32
  float* alpha = out0 + (size_t)BB * CC * NHOF;       // alpha: 8*1024*1024*8 f32

  short* WhT = (short*)d_ws;                          // 8,388,608 bf16 (16.78MB)
  float* res = (float*)(WhT + (size_t)8388608);       // 8,388,608 f32 (33.5MB)
  float* esg = res + (size_t)8388608;                 // 65,536 f32
  float* edg = esg + 65536;                           // 65,536 f32
  short* Wtb = (short*)(edg + 65536);                 // 262,144 bf16
  short* RWtb = Wtb + 262144;                         // 262,144 bf16

  k_prep<<<dim3(32, 8, 2), 256, 0, stream>>>(W, resW, Wtb, RWtb);
  k_gemm<<<dim3(16, 64), 256, 0, stream>>>(H, Wtb, RWtb, resb, av, WhT, res, esg, edg);
  k_attn<<<256, 256, 0, stream>>>(A, WhT, esg, edg, alpha, out0);
  k_ln  <<<BB * CC, 256, 0, stream>>>(res, gam, bet, out0);
}

// Round 4
// 484.039 us; speedup vs baseline: 1.6126x; 1.0892x over previous
//
#include <hip/hip_runtime.h>

#define BB 8
#define CC 1024
#define FF 256
#define NHH 8
#define OFF 128
#define NHOF 1024
#define KSCALE 0.9617966939259756f  // log2(e)/1.5

typedef __attribute__((ext_vector_type(8))) short s8v;
typedef __attribute__((ext_vector_type(4))) short s4v;
typedef __attribute__((ext_vector_type(4))) float f32x4;
typedef __attribute__((ext_vector_type(16))) float f32x16;

__device__ __forceinline__ ushort f2b(float f) {
  union { float f; uint u; } v; v.f = f;
  uint r = v.u + 0x7FFFu + ((v.u >> 16) & 1u);
  return (ushort)(r >> 16);
}

// ---------------- Kernel 0: transpose+cast W,res_W -> Wt,RWt bf16 [n][k] ----------------
__global__ __launch_bounds__(256) void k_prep(const float* __restrict__ W,
    const float* __restrict__ RW, short* __restrict__ Wt, short* __restrict__ RWt)
{
  __shared__ float st[32][33];
  const float* src = blockIdx.z ? RW : W;
  short* dst = blockIdx.z ? RWt : Wt;
  const int n0 = blockIdx.x * 32, k0 = blockIdx.y * 32;
  const int t = threadIdx.x;
  {
    int kr = t >> 3, nq = (t & 7) * 4;
    float4 v = *reinterpret_cast<const float4*>(src + (size_t)(k0 + kr) * NHOF + n0 + nq);
    st[kr][nq] = v.x; st[kr][nq + 1] = v.y; st[kr][nq + 2] = v.z; st[kr][nq + 3] = v.w;
  }
  __syncthreads();
  {
    int nr = t >> 3, kq = (t & 7) * 4;
    s4v pk;
    pk[0] = (short)f2b(st[kq + 0][nr]); pk[1] = (short)f2b(st[kq + 1][nr]);
    pk[2] = (short)f2b(st[kq + 2][nr]); pk[3] = (short)f2b(st[kq + 3][nr]);
    *reinterpret_cast<s4v*>(dst + (size_t)(n0 + nr) * FF + k0 + kq) = pk;
  }
}

// ---------------- Kernel 1: MFMA dual GEMM + e_src/e_dst epilogue ----------------
// nb 0..7: Wh = H@W -> WhT bf16 [b][h][f][j] (coalesced via LDS transpose), + e_src/e_dst
// nb 8..15: res = H@res_W + b (f32)
__global__ __launch_bounds__(256) void k_gemm(const float* __restrict__ H,
    const short* __restrict__ Wt, const short* __restrict__ RWt,
    const float* __restrict__ rb, const float* __restrict__ att,
    short* __restrict__ WhT, float* __restrict__ Rs,
    float* __restrict__ esg, float* __restrict__ edg)
{
  __shared__ short SU[8192];        // K-loop: As=SU[0:4096], Bs=SU[4096:8192]; epilogue: transpose buf
  __shared__ float ep[2][128][2];
  short* As = SU;
  short* Bs = SU + 4096;
  const int t = threadIdx.x, l = t & 63, w = t >> 6;
  const int wr = w >> 1, wc = w & 1;
  const int nb = blockIdx.x, m0 = blockIdx.y * 128;
  const bool isW = nb < 8;
  const int n0 = (nb & 7) * 128;
  const short* Bg = isW ? Wt : RWt;

  f32x4 acc[4][4];
#pragma unroll
  for (int mi = 0; mi < 4; ++mi)
#pragma unroll
    for (int ni = 0; ni < 4; ++ni)
#pragma unroll
      for (int r = 0; r < 4; ++r) acc[mi][ni][r] = 0.f;

  const int srow = t >> 1, skh = (t & 1) * 16;
  const float* hsrc = H + (size_t)(m0 + srow) * FF + skh;
  const short* bsrc = Bg + (size_t)(n0 + srow) * FF + skh;
  const int fr = l & 15, kg = (l >> 4) * 8;

  for (int k0 = 0; k0 < FF; k0 += 32) {
    float4 h0 = *reinterpret_cast<const float4*>(hsrc + k0);
    float4 h1 = *reinterpret_cast<const float4*>(hsrc + k0 + 4);
    float4 h2 = *reinterpret_cast<const float4*>(hsrc + k0 + 8);
    float4 h3 = *reinterpret_cast<const float4*>(hsrc + k0 + 12);
    s8v b0 = *reinterpret_cast<const s8v*>(bsrc + k0);
    s8v b1 = *reinterpret_cast<const s8v*>(bsrc + k0 + 8);
    s8v p0, p1;
    p0[0] = (short)f2b(h0.x); p0[1] = (short)f2b(h0.y); p0[2] = (short)f2b(h0.z); p0[3] = (short)f2b(h0.w);
    p0[4] = (short)f2b(h1.x); p0[5] = (short)f2b(h1.y); p0[6] = (short)f2b(h1.z); p0[7] = (short)f2b(h1.w);
    p1[0] = (short)f2b(h2.x); p1[1] = (short)f2b(h2.y); p1[2] = (short)f2b(h2.z); p1[3] = (short)f2b(h2.w);
    p1[4] = (short)f2b(h3.x); p1[5] = (short)f2b(h3.y); p1[6] = (short)f2b(h3.z); p1[7] = (short)f2b(h3.w);
    *reinterpret_cast<s8v*>(As + srow * 32 + skh) = p0;
    *reinterpret_cast<s8v*>(As + srow * 32 + skh + 8) = p1;
    *reinterpret_cast<s8v*>(Bs + srow * 32 + skh) = b0;
    *reinterpret_cast<s8v*>(Bs + srow * 32 + skh + 8) = b1;
    __syncthreads();
    s8v aF[4], bF[4];
#pragma unroll
    for (int mi = 0; mi < 4; ++mi)
      aF[mi] = *reinterpret_cast<const s8v*>(As + (wr * 64 + mi * 16 + fr) * 32 + kg);
#pragma unroll
    for (int ni = 0; ni < 4; ++ni)
      bF[ni] = *reinterpret_cast<const s8v*>(Bs + (wc * 64 + ni * 16 + fr) * 32 + kg);
#pragma unroll
    for (int mi = 0; mi < 4; ++mi)
#pragma unroll
      for (int ni = 0; ni < 4; ++ni)
        acc[mi][ni] = __builtin_amdgcn_mfma_f32_16x16x32_bf16(aF[mi], bF[ni], acc[mi][ni], 0, 0, 0);
    __syncthreads();
  }

  const int bb = m0 >> 10, jl0 = m0 & 1023;
  if (isW) {
    const int h = nb;
    // e_src/e_dst partials from f32 acc (into ep; consumed after chunk-0 barrier)
    float aS[4], aD[4];
#pragma unroll
    for (int ni = 0; ni < 4; ++ni) {
      int f = wc * 64 + ni * 16 + (l & 15);
      aS[ni] = att[h * 256 + f];
      aD[ni] = att[h * 256 + 128 + f];
    }
#pragma unroll
    for (int mi = 0; mi < 4; ++mi)
#pragma unroll
      for (int r = 0; r < 4; ++r) {
        float ps = acc[mi][0][r] * aS[0] + acc[mi][1][r] * aS[1] + acc[mi][2][r] * aS[2] + acc[mi][3][r] * aS[3];
        float pd = acc[mi][0][r] * aD[0] + acc[mi][1][r] * aD[1] + acc[mi][2][r] * aD[2] + acc[mi][3][r] * aD[3];
#pragma unroll
        for (int m = 1; m <= 8; m <<= 1) { ps += __shfl_xor(ps, m); pd += __shfl_xor(pd, m); }
        if ((l & 15) == 0) {
          int row = wr * 64 + mi * 16 + (l >> 4) * 4 + r;
          ep[wc][row][0] = ps; ep[wc][row][1] = pd;
        }
      }
    // WhT write via LDS transpose: 4 chunks of 32 f x 128 j (pad stride 136)
#pragma unroll
    for (int c = 0; c < 4; ++c) {
      if (wc == (c >> 1)) {
        const int nia = (c & 1) * 2;
#pragma unroll
        for (int mi = 0; mi < 4; ++mi)
#pragma unroll
          for (int nq = 0; nq < 2; ++nq) {
            const int ni = nia + nq;
            const int f_loc = nq * 16 + (l & 15);
            const int jloc = wr * 64 + mi * 16 + (l >> 4) * 4;
            s4v pk;
            pk[0] = (short)f2b(acc[mi][ni][0]); pk[1] = (short)f2b(acc[mi][ni][1]);
            pk[2] = (short)f2b(acc[mi][ni][2]); pk[3] = (short)f2b(acc[mi][ni][3]);
            *reinterpret_cast<s4v*>(SU + f_loc * 136 + jloc) = pk;
          }
      }
      __syncthreads();
      {
        const int f_loc = t >> 3, jq = t & 7;
        s8v v0 = *reinterpret_cast<const s8v*>(SU + f_loc * 136 + jq * 16);
        s8v v1 = *reinterpret_cast<const s8v*>(SU + f_loc * 136 + jq * 16 + 8);
        short* dst = WhT + (size_t)((bb * 8 + h) * 128 + c * 32 + f_loc) * 1024 + jl0 + jq * 16;
        *reinterpret_cast<s8v*>(dst) = v0;
        *reinterpret_cast<s8v*>(dst + 8) = v1;
      }
      __syncthreads();
    }
    // esg/edg (ep visible after chunk barriers)
    {
      int row = t >> 1, sel = t & 1;
      float v = ep[0][row][sel] + ep[1][row][sel];
      float* dst = sel ? edg : esg;
      dst[(size_t)((bb << 10) + jl0 + row) * 8 + h] = v;
    }
  } else {
#pragma unroll
    for (int mi = 0; mi < 4; ++mi)
#pragma unroll
      for (int ni = 0; ni < 4; ++ni) {
        int n = n0 + wc * 64 + ni * 16 + (l & 15);
        float bias = rb[n];
        int m = m0 + wr * 64 + mi * 16 + (l >> 4) * 4;
#pragma unroll
        for (int r = 0; r < 4; ++r)
          Rs[(size_t)(m + r) * NHOF + n] = acc[mi][ni][r] + bias;
      }
  }
}

// ---------------- Kernel 2: fused rowsum + softmax + alpha-out + MFMA PV ----------------
// grid 256 = (b, 32-row i-tile); 1024 threads (16 waves, 4/SIMD); ~66.4KB LDS
// Single barrier per 32-j step; alS double-buffered (XOR-swizzled 16B slots);
// B-fragments direct-from-global (WhT is L2-resident, [h][f][j] with j contiguous).
__global__ __launch_bounds__(1024) void k_attn(const float* __restrict__ A,
    const short* __restrict__ WhT, const float* __restrict__ esg,
    const float* __restrict__ edg, float* __restrict__ alp, float* __restrict__ ho)
{
  __shared__ short alSf[2 * 8 * 32 * 32];  // [buf][h][i][32j] bf16, swizzled: 32KB
  __shared__ float edKT[1024 * 8];         // e_dst*K [j][h] f32: 32KB
  __shared__ float esK[32 * 8];
  __shared__ float liS[32 * 8];
  __shared__ float rsS[32];

  const int t = threadIdx.x, l = t & 63, w = t >> 6;
  const int b = blockIdx.x >> 5, i0 = (blockIdx.x & 31) << 5;

  // stage e_dst*K (layout matches edg flat order) and e_src*K
#pragma unroll
  for (int c = 0; c < 8; ++c) {
    int idx = t + c * 1024;
    edKT[idx] = edg[(size_t)b * 8192 + idx] * KSCALE;
  }
  if (t < 256) esK[t] = esg[(size_t)((b << 10) + i0 + (t >> 3)) * 8 + (t & 7)] * KSCALE;

  const int i = t >> 5, jsub = t & 31;
  const float* Ar = A + (size_t)((b << 10) + i0 + i) * 1024;

  // pass 0: A row sums (32 lanes per row)
  {
    float s = 0.f;
#pragma unroll
    for (int c = 0; c < 8; ++c) {
      float4 v = *reinterpret_cast<const float4*>(Ar + jsub * 4 + c * 128);
      s += v.x + v.y + v.z + v.w;
    }
    s += __shfl_xor(s, 1); s += __shfl_xor(s, 2); s += __shfl_xor(s, 4);
    s += __shfl_xor(s, 8); s += __shfl_xor(s, 16);
    if (jsub == 0) rsS[i] = 1.f / (s + 1e-8f);
  }
  __syncthreads();

  // pass 1: softmax denominators (no max shift: scores bounded ~[-5,5])
  {
    const int ig = i0 + i;
    const float rs = rsS[i];
    float eK[8];
#pragma unroll
    for (int h2 = 0; h2 < 8; ++h2) eK[h2] = esK[i * 8 + h2];
    float lac = 0.f;  // accumulate all-h via per-h regs
    float lach[8] = {0, 0, 0, 0, 0, 0, 0, 0};
    (void)lac;
    for (int jj = 0; jj < 32; ++jj) {
      int j = jsub + jj * 32;
      float aij = Ar[j];
      float ea = (aij > 0.f || j == ig) ? exp2f(aij * rs * KSCALE) : 0.f;
      float4 e0 = *reinterpret_cast<const float4*>(edKT + j * 8);
      float4 e1 = *reinterpret_cast<const float4*>(edKT + j * 8 + 4);
      float ed[8] = {e0.x, e0.y, e0.z, e0.w, e1.x, e1.y, e1.z, e1.w};
#pragma unroll
      for (int h2 = 0; h2 < 8; ++h2) {
        float s = eK[h2] + ed[h2];
        s = fmaxf(s, 0.2f * s);
        lach[h2] = fmaf(exp2f(s), ea, lach[h2]);
      }
    }
#pragma unroll
    for (int h2 = 0; h2 < 8; ++h2) {
      float v = lach[h2];
      v += __shfl_xor(v, 1); v += __shfl_xor(v, 2); v += __shfl_xor(v, 4);
      v += __shfl_xor(v, 8); v += __shfl_xor(v, 16);
      if (jsub == 0) liS[i * 8 + h2] = 1.f / v;
    }
  }
  __syncthreads();

  // ---- pass 2 ----
  // producer role: (ip, jp) -> 8 heads of alpha per step
  const int ip = i, jp = jsub, igP = i0 + ip;
  const float rsP = rsS[ip];
  float eKP[8], liP[8];
#pragma unroll
  for (int h2 = 0; h2 < 8; ++h2) { eKP[h2] = esK[ip * 8 + h2]; liP[h2] = liS[ip * 8 + h2]; }
  const float* ArP = Ar;
  // MFMA role: wave w -> head h = w>>1, f-half = w&1
  const int hM = w >> 1, fh = w & 1;
  const short* Wb = WhT + ((size_t)(b * 8 + hM) << 17) + (size_t)(fh * 64 + (l & 31)) * 1024 + (l >> 5) * 8;
  f32x16 acc0, acc1;
#pragma unroll
  for (int r = 0; r < 16; ++r) { acc0[r] = 0.f; acc1[r] = 0.f; }

  float areg[8];
  // alpha for step k: j = k*32 + jp; computed one step ahead
  {
    const int j = jp;
    float aij = ArP[j];
    float ea = (aij > 0.f || j == igP) ? exp2f(aij * rsP * KSCALE) : 0.f;
    float4 e0 = *reinterpret_cast<const float4*>(edKT + j * 8);
    float4 e1 = *reinterpret_cast<const float4*>(edKT + j * 8 + 4);
    float ed[8] = {e0.x, e0.y, e0.z, e0.w, e1.x, e1.y, e1.z, e1.w};
#pragma unroll
    for (int h2 = 0; h2 < 8; ++h2) {
      float s = eKP[h2] + ed[h2];
      s = fmaxf(s, 0.2f * s);
      areg[h2] = exp2f(s) * ea * liP[h2];
    }
    float* ap = alp + (size_t)((b << 10) + igP) * 8192 + (size_t)j * 8;
    *reinterpret_cast<float4*>(ap)     = make_float4(areg[0], areg[1], areg[2], areg[3]);
    *reinterpret_cast<float4*>(ap + 4) = make_float4(areg[4], areg[5], areg[6], areg[7]);
  }

  const int swW = ((jp >> 3) ^ (ip & 3)) << 3;       // producer swizzled slot (shorts)
  const int swR = (l & 31) & 3;                      // consumer swizzle key
  for (int k = 0; k < 32; ++k) {
    const int buf = k & 1;
    {
      short* as = alSf + buf * 8192 + ip * 32 + swW + (jp & 7);
#pragma unroll
      for (int h2 = 0; h2 < 8; ++h2) as[h2 * 1024] = (short)f2b(areg[h2]);
    }
    __syncthreads();
    // B-fragments direct from global (L2-resident)
    s8v bf00 = *reinterpret_cast<const s8v*>(Wb + k * 32);
    s8v bf01 = *reinterpret_cast<const s8v*>(Wb + k * 32 + 16);
    s8v bf10 = *reinterpret_cast<const s8v*>(Wb + 32768 + k * 32);
    s8v bf11 = *reinterpret_cast<const s8v*>(Wb + 32768 + k * 32 + 16);
    // produce alpha for step k+1 (hides global-load latency)
    if (k < 31) {
      const int j = (k + 1) * 32 + jp;
      float aij = ArP[j];
      float ea = (aij > 0.f || j == igP) ? exp2f(aij * rsP * KSCALE) : 0.f;
      float4 e0 = *reinterpret_cast<const float4*>(edKT + j * 8);
      float4 e1 = *reinterpret_cast<const float4*>(edKT + j * 8 + 4);
      float ed[8] = {e0.x, e0.y, e0.z, e0.w, e1.x, e1.y, e1.z, e1.w};
#pragma unroll
      for (int h2 = 0; h2 < 8; ++h2) {
        float s = eKP[h2] + ed[h2];
        s = fmaxf(s, 0.2f * s);
        areg[h2] = exp2f(s) * ea * liP[h2];
      }
      float* ap = alp + (size_t)((b << 10) + igP) * 8192 + (size_t)j * 8;
      *reinterpret_cast<float4*>(ap)     = make_float4(areg[0], areg[1], areg[2], areg[3]);
      *reinterpret_cast<float4*>(ap + 4) = make_float4(areg[4], areg[5], areg[6], areg[7]);
    }
    // A-fragments from alS (swizzled, conflict-free b128)
    const short* afp = alSf + buf * 8192 + hM * 1024 + (l & 31) * 32;
    s8v af0 = *reinterpret_cast<const s8v*>(afp + ((((l >> 5)) ^ swR) << 3));
    s8v af1 = *reinterpret_cast<const s8v*>(afp + (((2 | (l >> 5)) ^ swR) << 3));
    acc0 = __builtin_amdgcn_mfma_f32_32x32x16_bf16(af0, bf00, acc0, 0, 0, 0);
    acc0 = __builtin_amdgcn_mfma_f32_32x32x16_bf16(af1, bf01, acc0, 0, 0, 0);
    acc1 = __builtin_amdgcn_mfma_f32_32x32x16_bf16(af0, bf10, acc1, 0, 0, 0);
    acc1 = __builtin_amdgcn_mfma_f32_32x32x16_bf16(af1, bf11, acc1, 0, 0, 0);
  }

  // epilogue: H_out (C/D layout: col=l&31, row=(reg&3)+8*(reg>>2)+4*(l>>5))
  {
    float* op = ho + (size_t)((b << 10) + i0) * 1024 + hM * 128 + fh * 64 + (l & 31);
#pragma unroll
    for (int reg = 0; reg < 16; ++reg) {
      int irow = (reg & 3) + 8 * (reg >> 2) + 4 * (l >> 5);
      op[(size_t)irow * 1024]      = acc0[reg];
      op[(size_t)irow * 1024 + 32] = acc1[reg];
    }
  }
}

// ---------------- Kernel 3: x = H_out + res ; LayerNorm ; ReLU (in-place) ----------------
__global__ __launch_bounds__(256) void k_ln(const float* __restrict__ Rs,
    const float* __restrict__ g, const float* __restrict__ bt, float* __restrict__ out)
{
  __shared__ float sm[8];
  const int row = blockIdx.x;
  const int t = threadIdx.x;
  size_t base = (size_t)row * NHOF + t * 4;
  float4 hv = *reinterpret_cast<const float4*>(out + base);
  float4 rv = *reinterpret_cast<const float4*>(Rs + base);
  float x0 = hv.x + rv.x, x1 = hv.y + rv.y, x2 = hv.z + rv.z, x3 = hv.w + rv.w;
  float s  = x0 + x1 + x2 + x3;
  float ss = x0 * x0 + x1 * x1 + x2 * x2 + x3 * x3;
#pragma unroll
  for (int m = 32; m; m >>= 1) { s += __shfl_xor(s, m); ss += __shfl_xor(ss, m); }
  if ((t & 63) == 0) { sm[t >> 6] = s; sm[4 + (t >> 6)] = ss; }
  __syncthreads();
  s  = sm[0] + sm[1] + sm[2] + sm[3];
  ss = sm[4] + sm[5] + sm[6] + sm[7];
  float mu = s * (1.f / 1024.f);
  float var = ss * (1.f / 1024.f) - mu * mu;
  float rstd = rsqrtf(var + 1e-5f);
  float4 gv = *reinterpret_cast<const float4*>(g + t * 4);
  float4 bv = *reinterpret_cast<const float4*>(bt + t * 4);
  float y0 = fmaxf((x0 - mu) * rstd * gv.x + bv.x, 0.f);
  float y1 = fmaxf((x1 - mu) * rstd * gv.y + bv.y, 0.f);
  float y2 = fmaxf((x2 - mu) * rstd * gv.z + bv.z, 0.f);
  float y3 = fmaxf((x3 - mu) * rstd * gv.w + bv.w, 0.f);
  *reinterpret_cast<float4*>(out + base) = make_float4(y0, y1, y2, y3);
}

extern "C" void kernel_launch(void* const* d_in, const int* in_sizes, int n_in,
                              void* d_out, int out_size, void* d_ws, size_t ws_size,
                              hipStream_t stream) {
  const float* H    = (const float*)d_in[0];
  const float* A    = (const float*)d_in[1];
  const float* W    = (const float*)d_in[2];
  const float* av   = (const float*)d_in[3];
  const float* resW = (const float*)d_in[4];
  const float* resb = (const float*)d_in[5];
  const float* gam  = (const float*)d_in[6];
  const float* bet  = (const float*)d_in[7];

  float* out0  = (float*)d_out;                       // relu(x): 8*1024*1024 f32
  float* alpha = out0 + (size_t)BB * CC * NHOF;       // alpha: 8*1024*1024*8 f32

  short* WhT = (short*)d_ws;                          // 8,388,608 bf16 (16.78MB)
  float* res = (float*)(WhT + (size_t)8388608);       // 8,388,608 f32 (33.5MB)
  float* esg = res + (size_t)8388608;                 // 65,536 f32
  float* edg = esg + 65536;                           // 65,536 f32
  short* Wtb = (short*)(edg + 65536);                 // 262,144 bf16
  short* RWtb = Wtb + 262144;                         // 262,144 bf16

  k_prep<<<dim3(32, 8, 2), 256, 0, stream>>>(W, resW, Wtb, RWtb);
  k_gemm<<<dim3(16, 64), 256, 0, stream>>>(H, Wtb, RWtb, resb, av, WhT, res, esg, edg);
  k_attn<<<256, 1024, 0, stream>>>(A, WhT, esg, edg, alpha, out0);
  k_ln  <<<BB * CC, 256, 0, stream>>>(res, gam, bet, out0);
}

// Round 6
// 478.216 us; speedup vs baseline: 1.6323x; 1.0122x over previous
//
#include <hip/hip_runtime.h>

#define BB 8
#define CC 1024
#define FF 256
#define NHH 8
#define OFF 128
#define NHOF 1024
#define KSCALE 0.9617966939259756f  // log2(e)/1.5

typedef __attribute__((ext_vector_type(8))) short s8v;
typedef __attribute__((ext_vector_type(4))) short s4v;
typedef __attribute__((ext_vector_type(4))) float f32x4;
typedef __attribute__((ext_vector_type(16))) float f32x16;

__device__ __forceinline__ ushort f2b(float f) {
  union { float f; uint u; } v; v.f = f;
  uint r = v.u + 0x7FFFu + ((v.u >> 16) & 1u);
  return (ushort)(r >> 16);
}

// ---------------- Kernel 0: prep ----------------
// z==0: W -> Wt bf16 [n][k]; z==1: res_W -> RWt bf16 [n][k]; z==2: H -> Hb bf16 (flat, 2,097,152 elems)
__global__ __launch_bounds__(256) void k_prep(const float* __restrict__ W,
    const float* __restrict__ RW, const float* __restrict__ H,
    short* __restrict__ Wt, short* __restrict__ RWt, short* __restrict__ Hb)
{
  const int t = threadIdx.x;
  if (blockIdx.z == 2) {
    // H has B*C*FF = 2,097,152 floats; 256 blocks x 8192 elems
    size_t base = ((size_t)(blockIdx.y * 32 + blockIdx.x)) * 8192 + t * 4;
#pragma unroll
    for (int c = 0; c < 8; ++c) {
      float4 v = *reinterpret_cast<const float4*>(H + base + c * 1024);
      s4v pk;
      pk[0] = (short)f2b(v.x); pk[1] = (short)f2b(v.y);
      pk[2] = (short)f2b(v.z); pk[3] = (short)f2b(v.w);
      *reinterpret_cast<s4v*>(Hb + base + c * 1024) = pk;
    }
    return;
  }
  __shared__ float st[32][33];
  const float* src = blockIdx.z ? RW : W;
  short* dst = blockIdx.z ? RWt : Wt;
  const int n0 = blockIdx.x * 32, k0 = blockIdx.y * 32;
  {
    int kr = t >> 3, nq = (t & 7) * 4;
    float4 v = *reinterpret_cast<const float4*>(src + (size_t)(k0 + kr) * NHOF + n0 + nq);
    st[kr][nq] = v.x; st[kr][nq + 1] = v.y; st[kr][nq + 2] = v.z; st[kr][nq + 3] = v.w;
  }
  __syncthreads();
  {
    int nr = t >> 3, kq = (t & 7) * 4;
    s4v pk;
    pk[0] = (short)f2b(st[kq + 0][nr]); pk[1] = (short)f2b(st[kq + 1][nr]);
    pk[2] = (short)f2b(st[kq + 2][nr]); pk[3] = (short)f2b(st[kq + 3][nr]);
    *reinterpret_cast<s4v*>(dst + (size_t)(n0 + nr) * FF + k0 + kq) = pk;
  }
}

// ---------------- Kernel 1: MFMA dual GEMM + e_src/e_dst epilogue ----------------
// nb 0..7: Wh = H@W -> WhT bf16 [b][h][f][j] (coalesced via LDS transpose), + e_src/e_dst
// nb 8..15: res = H@res_W + b (f32)
__global__ __launch_bounds__(256) void k_gemm(const short* __restrict__ Hb,
    const short* __restrict__ Wt, const short* __restrict__ RWt,
    const float* __restrict__ rb, const float* __restrict__ att,
    short* __restrict__ WhT, float* __restrict__ Rs,
    float* __restrict__ esg, float* __restrict__ edg)
{
  __shared__ short SU[8192];        // K-loop: As=SU[0:4096], Bs=SU[4096:8192]; epilogue: transpose buf
  __shared__ float ep[2][128][2];
  short* As = SU;
  short* Bs = SU + 4096;
  const int t = threadIdx.x, l = t & 63, w = t >> 6;
  const int wr = w >> 1, wc = w & 1;
  const int nb = blockIdx.x, m0 = blockIdx.y * 128;
  const bool isW = nb < 8;
  const int n0 = (nb & 7) * 128;
  const short* Bg = isW ? Wt : RWt;

  f32x4 acc[4][4];
#pragma unroll
  for (int mi = 0; mi < 4; ++mi)
#pragma unroll
    for (int ni = 0; ni < 4; ++ni)
#pragma unroll
      for (int r = 0; r < 4; ++r) acc[mi][ni][r] = 0.f;

  const int srow = t >> 1, skh = (t & 1) * 16;
  const short* hsrc = Hb + (size_t)(m0 + srow) * FF + skh;
  const short* bsrc = Bg + (size_t)(n0 + srow) * FF + skh;
  const int fr = l & 15, kg = (l >> 4) * 8;

  for (int k0 = 0; k0 < FF; k0 += 32) {
    s8v a0 = *reinterpret_cast<const s8v*>(hsrc + k0);
    s8v a1 = *reinterpret_cast<const s8v*>(hsrc + k0 + 8);
    s8v b0 = *reinterpret_cast<const s8v*>(bsrc + k0);
    s8v b1 = *reinterpret_cast<const s8v*>(bsrc + k0 + 8);
    *reinterpret_cast<s8v*>(As + srow * 32 + skh) = a0;
    *reinterpret_cast<s8v*>(As + srow * 32 + skh + 8) = a1;
    *reinterpret_cast<s8v*>(Bs + srow * 32 + skh) = b0;
    *reinterpret_cast<s8v*>(Bs + srow * 32 + skh + 8) = b1;
    __syncthreads();
    s8v aF[4], bF[4];
#pragma unroll
    for (int mi = 0; mi < 4; ++mi)
      aF[mi] = *reinterpret_cast<const s8v*>(As + (wr * 64 + mi * 16 + fr) * 32 + kg);
#pragma unroll
    for (int ni = 0; ni < 4; ++ni)
      bF[ni] = *reinterpret_cast<const s8v*>(Bs + (wc * 64 + ni * 16 + fr) * 32 + kg);
#pragma unroll
    for (int mi = 0; mi < 4; ++mi)
#pragma unroll
      for (int ni = 0; ni < 4; ++ni)
        acc[mi][ni] = __builtin_amdgcn_mfma_f32_16x16x32_bf16(aF[mi], bF[ni], acc[mi][ni], 0, 0, 0);
    __syncthreads();
  }

  const int bb = m0 >> 10, jl0 = m0 & 1023;
  if (isW) {
    const int h = nb;
    // e_src/e_dst partials from f32 acc (into ep; consumed after chunk barriers)
    float aS[4], aD[4];
#pragma unroll
    for (int ni = 0; ni < 4; ++ni) {
      int f = wc * 64 + ni * 16 + (l & 15);
      aS[ni] = att[h * 256 + f];
      aD[ni] = att[h * 256 + 128 + f];
    }
#pragma unroll
    for (int mi = 0; mi < 4; ++mi)
#pragma unroll
      for (int r = 0; r < 4; ++r) {
        float ps = acc[mi][0][r] * aS[0] + acc[mi][1][r] * aS[1] + acc[mi][2][r] * aS[2] + acc[mi][3][r] * aS[3];
        float pd = acc[mi][0][r] * aD[0] + acc[mi][1][r] * aD[1] + acc[mi][2][r] * aD[2] + acc[mi][3][r] * aD[3];
#pragma unroll
        for (int m = 1; m <= 8; m <<= 1) { ps += __shfl_xor(ps, m); pd += __shfl_xor(pd, m); }
        if ((l & 15) == 0) {
          int row = wr * 64 + mi * 16 + (l >> 4) * 4 + r;
          ep[wc][row][0] = ps; ep[wc][row][1] = pd;
        }
      }
    // WhT write via LDS transpose: 4 chunks of 32 f x 128 j (pad stride 136)
#pragma unroll
    for (int c = 0; c < 4; ++c) {
      if (wc == (c >> 1)) {
        const int nia = (c & 1) * 2;
#pragma unroll
        for (int mi = 0; mi < 4; ++mi)
#pragma unroll
          for (int nq = 0; nq < 2; ++nq) {
            const int ni = nia + nq;
            const int f_loc = nq * 16 + (l & 15);
            const int jloc = wr * 64 + mi * 16 + (l >> 4) * 4;
            s4v pk;
            pk[0] = (short)f2b(acc[mi][ni][0]); pk[1] = (short)f2b(acc[mi][ni][1]);
            pk[2] = (short)f2b(acc[mi][ni][2]); pk[3] = (short)f2b(acc[mi][ni][3]);
            *reinterpret_cast<s4v*>(SU + f_loc * 136 + jloc) = pk;
          }
      }
      __syncthreads();
      {
        const int f_loc = t >> 3, jq = t & 7;
        s8v v0 = *reinterpret_cast<const s8v*>(SU + f_loc * 136 + jq * 16);
        s8v v1 = *reinterpret_cast<const s8v*>(SU + f_loc * 136 + jq * 16 + 8);
        short* dst = WhT + (size_t)((bb * 8 + h) * 128 + c * 32 + f_loc) * 1024 + jl0 + jq * 16;
        *reinterpret_cast<s8v*>(dst) = v0;
        *reinterpret_cast<s8v*>(dst + 8) = v1;
      }
      __syncthreads();
    }
    // esg/edg
    {
      int row = t >> 1, sel = t & 1;
      float v = ep[0][row][sel] + ep[1][row][sel];
      float* dst = sel ? edg : esg;
      dst[(size_t)((bb << 10) + jl0 + row) * 8 + h] = v;
    }
  } else {
#pragma unroll
    for (int mi = 0; mi < 4; ++mi)
#pragma unroll
      for (int ni = 0; ni < 4; ++ni) {
        int n = n0 + wc * 64 + ni * 16 + (l & 15);
        float bias = rb[n];
        int m = m0 + wr * 64 + mi * 16 + (l >> 4) * 4;
#pragma unroll
        for (int r = 0; r < 4; ++r)
          Rs[(size_t)(m + r) * NHOF + n] = acc[mi][ni][r] + bias;
      }
  }
}

// ---------------- Kernel 2: fused rowsum + softmax + alpha + MFMA PV + LN + ReLU ----------------
// grid 256 = (b, 32-row i-tile); 1024 threads (16 waves, 4/SIMD)
__global__ __launch_bounds__(1024) void k_attn(const float* __restrict__ A,
    const short* __restrict__ WhT, const float* __restrict__ esg,
    const float* __restrict__ edg, const float* __restrict__ res,
    const float* __restrict__ gam, const float* __restrict__ bet,
    float* __restrict__ alp, float* __restrict__ out0)
{
  __shared__ short alSf[2 * 8 * 32 * 32];  // [buf][h][i][32j] bf16, swizzled: 32KB
  __shared__ float edKT[1024 * 8];         // e_dst*K [j][h] f32: 32KB
  __shared__ float esK[32 * 8];
  __shared__ float liS[32 * 8];
  __shared__ float rsS[32];
  __shared__ float lnP[2][32][16];         // LN partials [s/ss][row][wave]
  __shared__ float muS[32];
  __shared__ float sdS[32];

  const int t = threadIdx.x, l = t & 63, w = t >> 6;
  const int b = blockIdx.x >> 5, i0 = (blockIdx.x & 31) << 5;

  // stage e_dst*K and e_src*K
#pragma unroll
  for (int c = 0; c < 8; ++c) {
    int idx = t + c * 1024;
    edKT[idx] = edg[(size_t)b * 8192 + idx] * KSCALE;
  }
  if (t < 256) esK[t] = esg[(size_t)((b << 10) + i0 + (t >> 3)) * 8 + (t & 7)] * KSCALE;

  const int i = t >> 5, jsub = t & 31;
  const float* Ar = A + (size_t)((b << 10) + i0 + i) * 1024;

  // pass 0: A row sums (32 lanes per row)
  {
    float s = 0.f;
#pragma unroll
    for (int c = 0; c < 8; ++c) {
      float4 v = *reinterpret_cast<const float4*>(Ar + jsub * 4 + c * 128);
      s += v.x + v.y + v.z + v.w;
    }
    s += __shfl_xor(s, 1); s += __shfl_xor(s, 2); s += __shfl_xor(s, 4);
    s += __shfl_xor(s, 8); s += __shfl_xor(s, 16);
    if (jsub == 0) rsS[i] = 1.f / (s + 1e-8f);
  }
  __syncthreads();

  // pass 1: softmax denominators (no max shift: scores bounded ~[-5,5])
  {
    const int ig = i0 + i;
    const float rs = rsS[i];
    float eK[8];
#pragma unroll
    for (int h2 = 0; h2 < 8; ++h2) eK[h2] = esK[i * 8 + h2];
    float lach[8] = {0, 0, 0, 0, 0, 0, 0, 0};
    for (int jj = 0; jj < 32; ++jj) {
      int j = jsub + jj * 32;
      float aij = Ar[j];
      float ea = (aij > 0.f || j == ig) ? exp2f(aij * rs * KSCALE) : 0.f;
      float4 e0 = *reinterpret_cast<const float4*>(edKT + j * 8);
      float4 e1 = *reinterpret_cast<const float4*>(edKT + j * 8 + 4);
      float ed[8] = {e0.x, e0.y, e0.z, e0.w, e1.x, e1.y, e1.z, e1.w};
#pragma unroll
      for (int h2 = 0; h2 < 8; ++h2) {
        float s = eK[h2] + ed[h2];
        s = fmaxf(s, 0.2f * s);
        lach[h2] = fmaf(exp2f(s), ea, lach[h2]);
      }
    }
#pragma unroll
    for (int h2 = 0; h2 < 8; ++h2) {
      float v = lach[h2];
      v += __shfl_xor(v, 1); v += __shfl_xor(v, 2); v += __shfl_xor(v, 4);
      v += __shfl_xor(v, 8); v += __shfl_xor(v, 16);
      if (jsub == 0) liS[i * 8 + h2] = 1.f / v;
    }
  }
  __syncthreads();

  // ---- pass 2: producer (alpha) + consumer (MFMA PV), single barrier/step ----
  const int ip = i, jp = jsub, igP = i0 + ip;
  const float rsP = rsS[ip];
  float eKP[8], liP[8];
#pragma unroll
  for (int h2 = 0; h2 < 8; ++h2) { eKP[h2] = esK[ip * 8 + h2]; liP[h2] = liS[ip * 8 + h2]; }
  const float* ArP = Ar;
  const int hM = w >> 1, fh = w & 1;
  const short* Wb = WhT + ((size_t)(b * 8 + hM) << 17) + (size_t)(fh * 64 + (l & 31)) * 1024 + (l >> 5) * 8;
  f32x16 acc0, acc1;
#pragma unroll
  for (int r = 0; r < 16; ++r) { acc0[r] = 0.f; acc1[r] = 0.f; }

  float areg[8];
  {
    const int j = jp;
    float aij = ArP[j];
    float ea = (aij > 0.f || j == igP) ? exp2f(aij * rsP * KSCALE) : 0.f;
    float4 e0 = *reinterpret_cast<const float4*>(edKT + j * 8);
    float4 e1 = *reinterpret_cast<const float4*>(edKT + j * 8 + 4);
    float ed[8] = {e0.x, e0.y, e0.z, e0.w, e1.x, e1.y, e1.z, e1.w};
#pragma unroll
    for (int h2 = 0; h2 < 8; ++h2) {
      float s = eKP[h2] + ed[h2];
      s = fmaxf(s, 0.2f * s);
      areg[h2] = exp2f(s) * ea * liP[h2];
    }
    float* ap = alp + (size_t)((b << 10) + igP) * 8192 + (size_t)j * 8;
    *reinterpret_cast<float4*>(ap)     = make_float4(areg[0], areg[1], areg[2], areg[3]);
    *reinterpret_cast<float4*>(ap + 4) = make_float4(areg[4], areg[5], areg[6], areg[7]);
  }

  const int swW = ((jp >> 3) ^ (ip & 3)) << 3;       // producer swizzled slot (shorts)
  const int swR = (l & 31) & 3;                      // consumer swizzle key
  for (int k = 0; k < 32; ++k) {
    const int buf = k & 1;
    {
      short* as = alSf + buf * 8192 + ip * 32 + swW + (jp & 7);
#pragma unroll
      for (int h2 = 0; h2 < 8; ++h2) as[h2 * 1024] = (short)f2b(areg[h2]);
    }
    __syncthreads();
    s8v bf00 = *reinterpret_cast<const s8v*>(Wb + k * 32);
    s8v bf01 = *reinterpret_cast<const s8v*>(Wb + k * 32 + 16);
    s8v bf10 = *reinterpret_cast<const s8v*>(Wb + 32768 + k * 32);
    s8v bf11 = *reinterpret_cast<const s8v*>(Wb + 32768 + k * 32 + 16);
    if (k < 31) {
      const int j = (k + 1) * 32 + jp;
      float aij = ArP[j];
      float ea = (aij > 0.f || j == igP) ? exp2f(aij * rsP * KSCALE) : 0.f;
      float4 e0 = *reinterpret_cast<const float4*>(edKT + j * 8);
      float4 e1 = *reinterpret_cast<const float4*>(edKT + j * 8 + 4);
      float ed[8] = {e0.x, e0.y, e0.z, e0.w, e1.x, e1.y, e1.z, e1.w};
#pragma unroll
      for (int h2 = 0; h2 < 8; ++h2) {
        float s = eKP[h2] + ed[h2];
        s = fmaxf(s, 0.2f * s);
        areg[h2] = exp2f(s) * ea * liP[h2];
      }
      float* ap = alp + (size_t)((b << 10) + igP) * 8192 + (size_t)j * 8;
      *reinterpret_cast<float4*>(ap)     = make_float4(areg[0], areg[1], areg[2], areg[3]);
      *reinterpret_cast<float4*>(ap + 4) = make_float4(areg[4], areg[5], areg[6], areg[7]);
    }
    const short* afp = alSf + buf * 8192 + hM * 1024 + (l & 31) * 32;
    s8v af0 = *reinterpret_cast<const s8v*>(afp + ((((l >> 5)) ^ swR) << 3));
    s8v af1 = *reinterpret_cast<const s8v*>(afp + (((2 | (l >> 5)) ^ swR) << 3));
    acc0 = __builtin_amdgcn_mfma_f32_32x32x16_bf16(af0, bf00, acc0, 0, 0, 0);
    acc0 = __builtin_amdgcn_mfma_f32_32x32x16_bf16(af1, bf01, acc0, 0, 0, 0);
    acc1 = __builtin_amdgcn_mfma_f32_32x32x16_bf16(af0, bf10, acc1, 0, 0, 0);
    acc1 = __builtin_amdgcn_mfma_f32_32x32x16_bf16(af1, bf11, acc1, 0, 0, 0);
  }

  // ---- fused epilogue: x = H_out + res; LN; ReLU ----
  {
    const float* rp = res + ((size_t)((b << 10) + i0)) * 1024 + hM * 128 + fh * 64 + (l & 31);
#pragma unroll
    for (int reg = 0; reg < 16; ++reg) {
      int irow = (reg & 3) + 8 * (reg >> 2) + 4 * (l >> 5);
      acc0[reg] += rp[(size_t)irow * 1024];
      acc1[reg] += rp[(size_t)irow * 1024 + 32];
      float sp = acc0[reg] + acc1[reg];
      float sq = acc0[reg] * acc0[reg] + acc1[reg] * acc1[reg];
#pragma unroll
      for (int m = 1; m <= 16; m <<= 1) { sp += __shfl_xor(sp, m); sq += __shfl_xor(sq, m); }
      if ((l & 31) == 0) { lnP[0][irow][w] = sp; lnP[1][irow][w] = sq; }
    }
  }
  __syncthreads();
  if (t < 512) {
    int row = t >> 4, wv = t & 15;
    float sp = lnP[0][row][wv], sq = lnP[1][row][wv];
#pragma unroll
    for (int m = 1; m <= 8; m <<= 1) { sp += __shfl_xor(sp, m); sq += __shfl_xor(sq, m); }
    if (wv == 0) {
      float mu = sp * (1.f / 1024.f);
      float var = sq * (1.f / 1024.f) - mu * mu;
      muS[row] = mu;
      sdS[row] = rsqrtf(var + 1e-5f);
    }
  }
  __syncthreads();
  {
    const int colA = hM * 128 + fh * 64 + (l & 31);
    float g0 = gam[colA], g1 = gam[colA + 32];
    float b0 = bet[colA], b1 = bet[colA + 32];
    float* op = out0 + ((size_t)((b << 10) + i0)) * 1024 + colA;
#pragma unroll
    for (int reg = 0; reg < 16; ++reg) {
      int irow = (reg & 3) + 8 * (reg >> 2) + 4 * (l >> 5);
      float mu = muS[irow], rsd = sdS[irow];
      op[(size_t)irow * 1024]      = fmaxf((acc0[reg] - mu) * rsd * g0 + b0, 0.f);
      op[(size_t)irow * 1024 + 32] = fmaxf((acc1[reg] - mu) * rsd * g1 + b1, 0.f);
    }
  }
}

extern "C" void kernel_launch(void* const* d_in, const int* in_sizes, int n_in,
                              void* d_out, int out_size, void* d_ws, size_t ws_size,
                              hipStream_t stream) {
  const float* H    = (const float*)d_in[0];
  const float* A    = (const float*)d_in[1];
  const float* W    = (const float*)d_in[2];
  const float* av   = (const float*)d_in[3];
  const float* resW = (const float*)d_in[4];
  const float* resb = (const float*)d_in[5];
  const float* gam  = (const float*)d_in[6];
  const float* bet  = (const float*)d_in[7];

  float* out0  = (float*)d_out;                       // relu(x): 8*1024*1024 f32
  float* alpha = out0 + (size_t)BB * CC * NHOF;       // alpha: 8*1024*1024*8 f32

  short* WhT = (short*)d_ws;                          // 8,388,608 bf16 (16.78MB)
  float* res = (float*)(WhT + (size_t)8388608);       // 8,388,608 f32 (33.5MB)
  float* esg = res + (size_t)8388608;                 // 65,536 f32
  float* edg = esg + 65536;                           // 65,536 f32
  short* Wtb = (short*)(edg + 65536);                 // 262,144 bf16
  short* RWtb = Wtb + 262144;                         // 262,144 bf16
  short* Hb   = RWtb + 262144;                        // 2,097,152 bf16 (4.2MB)

  k_prep<<<dim3(32, 8, 3), 256, 0, stream>>>(W, resW, H, Wtb, RWtb, Hb);
  k_gemm<<<dim3(16, 64), 256, 0, stream>>>(Hb, Wtb, RWtb, resb, av, WhT, res, esg, edg);
  k_attn<<<256, 1024, 0, stream>>>(A, WhT, esg, edg, res, gam, bet, alpha, out0);
}